// Round 1
// baseline (5775.991 us; speedup 1.0000x reference)
//
#include <hip/hip_runtime.h>
#include <stdint.h>

// LSTM: B=256, T=512, F=32, U=350, gates i,f,g(relu),o ; h_new = o*relu(c_new)
// out[b,t] = h . dense_w + dense_b
//
// Design:
//  - Batch-partition: 16 blocks x 16 rows; each block runs the full T=512 scan
//    independently (recurrence independent across batch -> no grid sync).
//  - Per step: z[16, 4*352] = [x_t | h | 1 | 0][16,384] @ W[384, 4*352] via
//    mfma_f32_16x16x32_bf16. Weights pre-swizzled to B-fragment order by a
//    prep kernel (contiguous dwordx4 per lane, streamed from L2 each step).
//  - Gate padding 350->352: 22 tiles/gate, wave w (of 11) owns gate-relative
//    tiles {2w, 2w+1} for ALL 4 gates -> gate math + c-state fully in-register.
//  - h state: fp32 in update, rounded to bf16 into LDS A-region for next step.
//  - bias folded as K-row 382 with input element fixed at 1.0.

#define T_    512
#define F_    32
#define U_    350
#define G4    1400          // 4*U
#define NB    16            // batch rows per block
#define NBLK  16            // blocks (NB*NBLK = 256)
#define KC    12            // K chunks of 32 (K padded to 384)
#define NT    88            // N tiles: 4 gates * 22
#define NW    11            // waves per block
#define BLK   (NW*64)       // 704 threads
#define ROWS  392           // LDS row stride in bf16 elems (384 + 8 pad)

typedef __attribute__((ext_vector_type(8))) short  short8;
typedef __attribute__((ext_vector_type(4))) float  float4_;

__device__ __forceinline__ short f2bf(float f) {
  union { float f; uint32_t u; } v; v.f = f;
  return (short)((v.u + 0x7FFFu + ((v.u >> 16) & 1u)) >> 16);
}

// ---- prep: build W_swz[kc][tile][lane][8] bf16 in B-fragment order ----
// tile = g*22 + j ; col_g = j*16 + (lane&15) ; k = kc*32 + (lane>>4)*8 + jj
// source: k<32 -> kernel[k][col] ; k<382 -> rk[k-32][col] ; k==382 -> bias ; else 0
__global__ void prep_kernel(const float* __restrict__ kern,
                            const float* __restrict__ rk,
                            const float* __restrict__ bias,
                            short* __restrict__ wswz) {
  const int tile = blockIdx.x;       // 0..87
  const int lane = threadIdx.x;      // 0..63
  const int g    = tile / 22;
  const int j    = tile % 22;
  const int colg = j * 16 + (lane & 15);
  const int src  = g * U_ + colg;
  const bool valid = (colg < U_);
  const int kbase = (lane >> 4) * 8;
  for (int kc = 0; kc < KC; ++kc) {
    short8 pack;
    #pragma unroll
    for (int jj = 0; jj < 8; ++jj) {
      int k = kc * 32 + kbase + jj;
      float v = 0.f;
      if (valid) {
        if (k < F_)            v = kern[k * G4 + src];
        else if (k < F_ + U_)  v = rk[(k - F_) * G4 + src];
        else if (k == F_ + U_) v = bias[src];
      }
      pack[jj] = f2bf(v);
    }
    *(short8*)(wswz + (((size_t)kc * NT + tile) * 64 + lane) * 8) = pack;
  }
}

// ---- main persistent scan kernel ----
__global__ __launch_bounds__(BLK, 3)
void lstm_kernel(const float* __restrict__ x,
                 const float* __restrict__ dense_w,
                 const float* __restrict__ dense_b,
                 const short* __restrict__ wswz,
                 float* __restrict__ out) {
  __shared__ short insh[NB * ROWS];       // [x_t(32) | h(350) | 1.0 | 0 | pad]
  __shared__ float outpart[NW][NB];

  const int tid  = threadIdx.x;
  const int lane = tid & 63;
  const int w    = tid >> 6;              // wave 0..10
  const int l15  = lane & 15;
  const int quad = lane >> 4;
  const int bbase = blockIdx.x * NB;

  // zero A-region; plant bf16 1.0 at k==382 (bias row input)
  for (int idx = tid; idx < NB * ROWS; idx += BLK)
    insh[idx] = ((idx % ROWS) == 382) ? (short)0x3F80 : (short)0;
  __syncthreads();

  // x_0 into LDS (512 threads: row=tid>>5, col=tid&31)
  const int xm = tid >> 5, xc = tid & 31;
  const bool xth = (tid < NB * F_);
  if (xth) insh[xm * ROWS + xc] = f2bf(x[((size_t)(bbase + xm) * T_ + 0) * F_ + xc]);

  // per-lane constants: gate-relative columns this lane owns
  const int cg0 = (2 * w + 0) * 16 + l15;
  const int cg1 = (2 * w + 1) * 16 + l15;
  const float dw0 = (cg0 < U_) ? dense_w[cg0] : 0.f;
  const float dw1 = (cg1 < U_) ? dense_w[cg1] : 0.f;
  const float db0 = dense_b[0];

  float c_state[2][4];
  #pragma unroll
  for (int i = 0; i < 2; ++i)
    #pragma unroll
    for (int r = 0; r < 4; ++r) c_state[i][r] = 0.f;

  __syncthreads();

  float xv = 0.f;
  #pragma unroll 1
  for (int t = 0; t < T_; ++t) {
    // prefetch x_{t+1} into a register (overlaps GEMM; LDS write after barrier)
    if (xth && (t + 1) < T_)
      xv = x[((size_t)(bbase + xm) * T_ + (t + 1)) * F_ + xc];

    float4_ acc[4][2];
    #pragma unroll
    for (int g = 0; g < 4; ++g)
      #pragma unroll
      for (int i = 0; i < 2; ++i) acc[g][i] = (float4_){0.f, 0.f, 0.f, 0.f};

    // GEMM: z += A[16,384] @ W[384, 4*352]  (this wave: tiles g*22 + 2w + i)
    #pragma unroll 2
    for (int kc = 0; kc < KC; ++kc) {
      short8 a = *(const short8*)(&insh[l15 * ROWS + kc * 32 + quad * 8]);
      #pragma unroll
      for (int g = 0; g < 4; ++g) {
        #pragma unroll
        for (int i = 0; i < 2; ++i) {
          short8 b = *(const short8*)(&wswz[(((size_t)kc * NT + g * 22 + 2 * w + i) * 64 + lane) * 8]);
          acc[g][i] = __builtin_amdgcn_mfma_f32_16x16x32_bf16(a, b, acc[g][i], 0, 0, 0);
        }
      }
    }
    __syncthreads();   // all A-reads done; safe to overwrite h / x regions

    // update phase: gates in-register. D layout: row=(lane>>4)*4+r, col=l15.
    float pr[4] = {0.f, 0.f, 0.f, 0.f};
    #pragma unroll
    for (int i = 0; i < 2; ++i) {
      const int cgi = (i == 0) ? cg0 : cg1;
      const float dwi = (i == 0) ? dw0 : dw1;
      const bool v = (cgi < U_);
      #pragma unroll
      for (int r = 0; r < 4; ++r) {
        float zi = acc[0][i][r], zf = acc[1][i][r];
        float zg = acc[2][i][r], zo = acc[3][i][r];
        float ig = __builtin_amdgcn_rcpf(1.f + __expf(-zi));
        float fg = __builtin_amdgcn_rcpf(1.f + __expf(-zf));
        float gg = fmaxf(zg, 0.f);
        float og = __builtin_amdgcn_rcpf(1.f + __expf(-zo));
        float cn = fg * c_state[i][r] + ig * gg;
        c_state[i][r] = cn;
        float hn = og * fmaxf(cn, 0.f);
        if (v) {
          int m = quad * 4 + r;
          insh[m * ROWS + F_ + cgi] = f2bf(hn);   // next step's A operand
          pr[r] += hn * dwi;
        }
      }
    }
    // write prefetched x_{t+1}
    if (xth) insh[xm * ROWS + xc] = f2bf(xv);

    // dense head: reduce pr over the 16-lane column group -> per-wave partial
    #pragma unroll
    for (int r = 0; r < 4; ++r) {
      float s = pr[r];
      s += __shfl_xor(s, 1);
      s += __shfl_xor(s, 2);
      s += __shfl_xor(s, 4);
      s += __shfl_xor(s, 8);
      if (l15 == 0) outpart[w][quad * 4 + r] = s;
    }
    __syncthreads();   // h/x written, outpart ready

    if (tid < NB) {
      float s = db0;
      #pragma unroll
      for (int ww = 0; ww < NW; ++ww) s += outpart[ww][tid];
      out[(size_t)(bbase + tid) * T_ + t] = s;
    }
  }
}

extern "C" void kernel_launch(void* const* d_in, const int* in_sizes, int n_in,
                              void* d_out, int out_size, void* d_ws, size_t ws_size,
                              hipStream_t stream) {
  const float* x    = (const float*)d_in[0];
  const float* kern = (const float*)d_in[1];
  const float* rk   = (const float*)d_in[2];
  const float* bias = (const float*)d_in[3];
  const float* dw   = (const float*)d_in[4];
  const float* db   = (const float*)d_in[5];
  float* out  = (float*)d_out;
  short* wswz = (short*)d_ws;   // 88*12*64*8*2B ~= 1.03 MB

  prep_kernel<<<NT, 64, 0, stream>>>(kern, rk, bias, wswz);
  lstm_kernel<<<NBLK, BLK, 0, stream>>>(x, dw, db, wswz, out);
}

// Round 2
// 5016.372 us; speedup vs baseline: 1.1514x; 1.1514x over previous
//
#include <hip/hip_runtime.h>
#include <stdint.h>

// LSTM B=256,T=512,F=32,U=350; gates i,f,g(relu),o; h=o*relu(c); out=h.dw+db
//
// R2 design: weight-stationary-in-registers, N-split across blocks.
//  - 16 batch groups x 11 column-blocks = 176 blocks (<=256 CUs -> co-resident).
//  - Block (grp,j) owns gate-relative cols [32j,32j+32) of ALL 4 gates =
//    8 MFMA tiles. Per wave (4 waves = 4 gates): 2 tiles x 12kc x 16B/lane
//    = 96 VGPRs of bf16 weights, loaded ONCE. No per-step weight traffic.
//  - h exchanged per step through global hbuf (ping-pong depth 2) + per-(grp,t)
//    release counters. A-fragments for the GEMM load DIRECTLY from hbuf/xbf
//    (16B/lane contiguous); hbuf col c corresponds to K row 32+c, with
//    c=350 pinned to 1.0 (bias row) and c=351 to 0.
//  - z cross-gate exchange via 10KB LDS; c-state in registers.
//  - dense head: per-block partials to wpart[grp][j][row][t]; tiny final
//    reduce kernel sums 11 partials (d_out fully written there).

#define T_   512
#define F_   32
#define U_   350
#define G4   1400
#define NGRP 16
#define NB   16
#define NCB  11
#define KC   12
#define NT   88
#define HROW 352

typedef __attribute__((ext_vector_type(8))) short  short8;
typedef __attribute__((ext_vector_type(4))) short  short4_;
typedef __attribute__((ext_vector_type(4))) float  float4_;

__device__ __forceinline__ short f2bf(float f) {
  union { float f; uint32_t u; } v; v.f = f;
  return (short)((v.u + 0x7FFFu + ((v.u >> 16) & 1u)) >> 16);
}

// ---- workspace layout (bytes) ----
#define SZ_W     (NT*KC*64*8*2u)                        // 1,081,344
#define OFF_XBF  ((SZ_W + 255u) & ~255u)
#define SZ_XBF   (256u*T_*F_*2u)                        // 8,388,608
#define OFF_HBUF ((OFF_XBF + SZ_XBF + 255u) & ~255u)
#define SZ_HBUF  (NGRP*2u*NB*HROW*2u)                   // 360,448
#define OFF_CNT  ((OFF_HBUF + SZ_HBUF + 255u) & ~255u)
#define SZ_CNT   (NGRP*T_*4u)                           // 32,768
#define OFF_WP   ((OFF_CNT + SZ_CNT + 255u) & ~255u)
#define SZ_WP    (NGRP*NCB*NB*T_*4u)                    // 5,767,168

// ---- prep: W_swz[kc][tile][lane][8] bf16 in MFMA B-fragment order ----
// tile = gate*22 + jt ; col_g = jt*16 + (lane&15) ; k = kc*32 + (lane>>4)*8 + jj
__global__ void prep_w(const float* __restrict__ kern,
                       const float* __restrict__ rk,
                       const float* __restrict__ bias,
                       short* __restrict__ wswz) {
  const int tile = blockIdx.x, lane = threadIdx.x;
  const int g = tile / 22, jt = tile % 22;
  const int colg = jt * 16 + (lane & 15);
  const int src = g * U_ + colg;
  const bool valid = (colg < U_);
  const int kbase = (lane >> 4) * 8;
  for (int kc = 0; kc < KC; ++kc) {
    short8 pack;
    #pragma unroll
    for (int jj = 0; jj < 8; ++jj) {
      int k = kc * 32 + kbase + jj;
      float v = 0.f;
      if (valid) {
        if (k < F_)            v = kern[k * G4 + src];
        else if (k < F_ + U_)  v = rk[(k - F_) * G4 + src];
        else if (k == F_ + U_) v = bias[src];
      }
      pack[jj] = f2bf(v);
    }
    *(short8*)(wswz + (((size_t)kc * NT + tile) * 64 + lane) * 8) = pack;
  }
}

// ---- prep: x f32 -> bf16 (A-operand direct-load layout [b][t][f]) ----
__global__ void prep_x(const float* __restrict__ x, short* __restrict__ xbf) {
  int i = (blockIdx.x * 256 + threadIdx.x) * 4;
  float4_ v = *(const float4_*)(x + i);
  short4_ o;
  #pragma unroll
  for (int jj = 0; jj < 4; ++jj) o[jj] = f2bf(v[jj]);
  *(short4_*)(xbf + i) = o;
}

// ---- init: zero counters; hbuf slot1 = h_{-1} = 0 (+bias 1.0 at c=350) ----
__global__ void init_sync(short* __restrict__ hbuf, uint32_t* __restrict__ cnt) {
  int i = blockIdx.x * 256 + threadIdx.x;
  if (i < NGRP * NB * HROW) {
    int grp = i / (NB * HROW), rem = i % (NB * HROW);
    int c = rem % HROW;
    hbuf[(grp * 2 + 1) * NB * HROW + rem] = (c == 350) ? (short)0x3F80 : (short)0;
  }
  if (i < NGRP * T_) cnt[i] = 0;
}

// ---- main: persistent per-(group, col-slice) scan ----
__global__ __launch_bounds__(256, 1)
void lstm_kernel(const short* __restrict__ xbf, const short* __restrict__ wswz,
                 short* __restrict__ hbuf, uint32_t* __restrict__ cnt,
                 float* __restrict__ wpart, const float* __restrict__ dense_w) {
  __shared__ float zsh[4][2][16][20];   // [gate][tile][col16][row16+pad4]

  const int tid  = threadIdx.x;
  const int lane = tid & 63;
  const int ww   = tid >> 6;            // wave = gate 0..3
  const int l15  = lane & 15;
  const int quad = lane >> 4;
  const int grp  = blockIdx.x & 15;     // same-XCD swizzle for a group's blocks
  const int j    = blockIdx.x >> 4;     // column block 0..10

  // weight slice -> registers (once): tiles {ww*22 + 2j, +1}
  short8 wreg[KC][2];
  #pragma unroll
  for (int kc = 0; kc < KC; ++kc)
    #pragma unroll
    for (int i = 0; i < 2; ++i)
      wreg[kc][i] = *(const short8*)(wswz +
          (((size_t)kc * NT + (ww * 22 + 2 * j + i)) * 64 + lane) * 8);

  const int ucol = lane & 31, half = lane >> 5;
  const int gcol = 32 * j + ucol;                 // this lane's h column
  const float dwv = (gcol < U_) ? dense_w[gcol] : 0.f;
  const int urow0 = 4 * ww + 2 * half;            // update rows urow0, urow0+1
  float cst[2] = {0.f, 0.f};

  const short* xrow = xbf + ((size_t)(grp * NB + l15) * T_) * F_ + quad * 8;
  short* hb = hbuf + (size_t)grp * 2 * NB * HROW;
  uint32_t* cg = cnt + grp * T_;

  #pragma unroll 1
  for (int t = 0; t < T_; ++t) {
    short8 axf = *(const short8*)(xrow + t * F_);   // x A-frag (indep of spin)

    if (t > 0) {
      uint32_t v;
      do {
        uint32_t c0 = 0;
        if (lane == 0)
          c0 = __hip_atomic_load(cg + (t - 1), __ATOMIC_RELAXED,
                                 __HIP_MEMORY_SCOPE_AGENT);
        v = (uint32_t)__shfl((int)c0, 0);
      } while (v < NCB);
      __builtin_amdgcn_fence(__ATOMIC_ACQUIRE, "agent");
    }

    // GEMM: A direct from hbuf slot (t+1)&1 ( == (t-1)&1 ), B from registers
    const short* hrd = hb + ((size_t)((t + 1) & 1)) * NB * HROW
                          + (size_t)l15 * HROW + quad * 8;
    float4_ acc[2][2];
    #pragma unroll
    for (int i = 0; i < 2; ++i)
      #pragma unroll
      for (int p = 0; p < 2; ++p) acc[i][p] = (float4_){0.f, 0.f, 0.f, 0.f};
    #pragma unroll
    for (int kc = 0; kc < KC; ++kc) {
      short8 a = (kc == 0) ? axf : *(const short8*)(hrd + 32 * (kc - 1));
      acc[0][kc & 1] = __builtin_amdgcn_mfma_f32_16x16x32_bf16(a, wreg[kc][0], acc[0][kc & 1], 0, 0, 0);
      acc[1][kc & 1] = __builtin_amdgcn_mfma_f32_16x16x32_bf16(a, wreg[kc][1], acc[1][kc & 1], 0, 0, 0);
    }
    #pragma unroll
    for (int i = 0; i < 2; ++i) {
      float4_ s = acc[i][0] + acc[i][1];
      *(float4_*)&zsh[ww][i][l15][quad * 4] = s;   // [col][rows quad*4..+3]
    }
    __syncthreads();

    // gate update: lane handles (rows urow0,urow0+1) x col ucol
    short* hwr = hb + ((size_t)(t & 1)) * NB * HROW;
    float pr[2];
    #pragma unroll
    for (int rr = 0; rr < 2; ++rr) {
      int row = urow0 + rr;
      float zi = zsh[0][ucol >> 4][ucol & 15][row];
      float zf = zsh[1][ucol >> 4][ucol & 15][row];
      float zg = zsh[2][ucol >> 4][ucol & 15][row];
      float zo = zsh[3][ucol >> 4][ucol & 15][row];
      float ig = __builtin_amdgcn_rcpf(1.f + __expf(-zi));
      float fg = __builtin_amdgcn_rcpf(1.f + __expf(-zf));
      float gg = fmaxf(zg, 0.f);
      float og = __builtin_amdgcn_rcpf(1.f + __expf(-zo));
      float cn = fg * cst[rr] + ig * gg;
      cst[rr] = cn;
      float hn = og * fmaxf(cn, 0.f);
      short hs = f2bf(hn);
      if (gcol == 350) hs = (short)0x3F80;   // bias row input stays 1.0
      else if (gcol == 351) hs = 0;
      hwr[row * HROW + gcol] = hs;
      pr[rr] = hn * dwv;
    }
    // dense-head partial: reduce over 32 cols (stays within 32-lane half)
    #pragma unroll
    for (int rr = 0; rr < 2; ++rr) {
      float s = pr[rr];
      s += __shfl_xor(s, 1);  s += __shfl_xor(s, 2);  s += __shfl_xor(s, 4);
      s += __shfl_xor(s, 8);  s += __shfl_xor(s, 16);
      if (ucol == 0)
        wpart[(((size_t)grp * NCB + j) * NB + urow0 + rr) * T_ + t] = s;
    }
    __syncthreads();   // all h stores issued & drained (vmcnt0 at barrier)

    if (tid == 0) {
      __builtin_amdgcn_fence(__ATOMIC_RELEASE, "agent");
      __hip_atomic_fetch_add(cg + t, 1u, __ATOMIC_RELAXED,
                             __HIP_MEMORY_SCOPE_AGENT);
    }
  }
}

// ---- final: out[b,t] = db + sum_j wpart[grp][j][row][t] ----
__global__ void reduce_out(const float* __restrict__ wpart,
                           const float* __restrict__ dense_b,
                           float* __restrict__ out) {
  int i = blockIdx.x * 256 + threadIdx.x;   // i = b*T + t
  int b = i >> 9, t = i & 511;
  int grp = b >> 4, row = b & 15;
  float s = dense_b[0];
  #pragma unroll
  for (int j = 0; j < NCB; ++j)
    s += wpart[(((size_t)grp * NCB + j) * NB + row) * T_ + t];
  out[i] = s;
}

extern "C" void kernel_launch(void* const* d_in, const int* in_sizes, int n_in,
                              void* d_out, int out_size, void* d_ws, size_t ws_size,
                              hipStream_t stream) {
  const float* x    = (const float*)d_in[0];
  const float* kern = (const float*)d_in[1];
  const float* rk   = (const float*)d_in[2];
  const float* bias = (const float*)d_in[3];
  const float* dw   = (const float*)d_in[4];
  const float* db   = (const float*)d_in[5];
  float* out = (float*)d_out;

  char* ws = (char*)d_ws;
  short*    wswz = (short*)(ws);
  short*    xbf  = (short*)(ws + OFF_XBF);
  short*    hbuf = (short*)(ws + OFF_HBUF);
  uint32_t* cnt  = (uint32_t*)(ws + OFF_CNT);
  float*    wpart= (float*)(ws + OFF_WP);

  prep_w<<<NT, 64, 0, stream>>>(kern, rk, bias, wswz);
  prep_x<<<(256 * T_ * F_) / (256 * 4), 256, 0, stream>>>(x, xbf);
  init_sync<<<(NGRP * NB * HROW + 255) / 256, 256, 0, stream>>>(hbuf, cnt);
  lstm_kernel<<<NGRP * NCB, 256, 0, stream>>>(xbf, wswz, hbuf, cnt, wpart, dw);
  reduce_out<<<(256 * T_) / 256, 256, 0, stream>>>(wpart, db, out);
}